// Round 11
// baseline (686.807 us; speedup 1.0000x reference)
//
#include <hip/hip_runtime.h>
#include <cstdint>

typedef unsigned short u16;
typedef unsigned int   u32;
typedef __attribute__((ext_vector_type(8))) short bf16x8;
typedef __attribute__((ext_vector_type(4))) float f32x4;

#define D_DIM 1000
#define C_IN  1024
#define HW    256
#define S_DIM 512
#define Q_DIM 64

__device__ __forceinline__ u16 f2b(float x) {
    u32 u = __builtin_bit_cast(u32, x);
    u32 r = (u + 0x7FFFu + ((u >> 16) & 1u)) >> 16;
    return (u16)r;
}
__device__ __forceinline__ float b2f(u16 h) {
    u32 u = ((u32)h) << 16;
    return __builtin_bit_cast(float, u);
}
__device__ __forceinline__ float ftanh(float x) {
    float e = __expf(2.f * x);
    return 1.f - 2.f / (e + 1.f);
}

#define GLOAD(ldsptr, gptr) \
    __builtin_amdgcn_global_load_lds( \
        (const __attribute__((address_space(1))) unsigned int*)(gptr), \
        (__attribute__((address_space(3))) unsigned int*)(ldsptr), 16, 0, 0)

// ---------------------------------------------------------------------------
// k_prepf: feat [b][1024 c][256 hw] fp32 -> featT_hi/lo bf16 [b][512 s][1024 c]
// ---------------------------------------------------------------------------
__global__ __launch_bounds__(256) void k_prepf(
    const float* __restrict__ feat_l, const float* __restrict__ feat_f,
    u16* __restrict__ fT_hi, u16* __restrict__ fT_lo)
{
    int bid = blockIdx.x;
    int ct = bid & 15, ht = (bid >> 4) & 3, half_ = (bid >> 6) & 1, b = bid >> 7;
    const float* src = (half_ ? feat_l : feat_f) + (size_t)b * C_IN * HW;
    __shared__ float T[64][65];
    int tid = threadIdx.x;
    {
        int cl = tid >> 2, h16 = (tid & 3) * 16;
        const float* p = src + (size_t)(ct * 64 + cl) * 256 + ht * 64 + h16;
        #pragma unroll
        for (int j = 0; j < 4; j++) {
            float4 v = *(const float4*)(p + j * 4);
            T[h16 + j * 4 + 0][cl] = v.x;
            T[h16 + j * 4 + 1][cl] = v.y;
            T[h16 + j * 4 + 2][cl] = v.z;
            T[h16 + j * 4 + 3][cl] = v.w;
        }
    }
    __syncthreads();
    {
        int hl = tid >> 2, c16 = (tid & 3) * 16;
        int srow = b * 512 + half_ * 256 + ht * 64 + hl;
        bf16x8 vh[2], vl[2];
        #pragma unroll
        for (int g = 0; g < 2; g++)
            #pragma unroll
            for (int j = 0; j < 8; j++) {
                float x = T[hl][c16 + g * 8 + j];
                u16 hh = f2b(x);
                vh[g][j] = (short)hh;
                vl[g][j] = (short)f2b(x - b2f(hh));
            }
        size_t o = (size_t)srow * 1024 + ct * 64 + c16;
        *(bf16x8*)(fT_hi + o) = vh[0];
        *(bf16x8*)(fT_hi + o + 8) = vh[1];
        *(bf16x8*)(fT_lo + o) = vl[0];
        *(bf16x8*)(fT_lo + o + 8) = vl[1];
    }
}

// ---------------------------------------------------------------------------
// k_prepcw: cw [1000][1024] fp32 -> cw_hi/lo [1024][1024] bf16
// ---------------------------------------------------------------------------
__global__ __launch_bounds__(256) void k_prepcw(
    const float* __restrict__ cw, u16* __restrict__ cwh, u16* __restrict__ cwl)
{
    int d = blockIdx.x;
    int c4 = threadIdx.x * 4;
    ushort4 h = make_ushort4(0, 0, 0, 0), lo = make_ushort4(0, 0, 0, 0);
    if (d < D_DIM) {
        float4 v = *(const float4*)(cw + (size_t)d * 1024 + c4);
        float a[4] = {v.x, v.y, v.z, v.w};
        u16* ph = (u16*)&h; u16* pl = (u16*)&lo;
        #pragma unroll
        for (int j = 0; j < 4; j++) {
            ph[j] = f2b(a[j]);
            pl[j] = f2b(a[j] - b2f(ph[j]));
        }
    }
    *(ushort4*)(cwh + (size_t)d * 1024 + c4) = h;
    *(ushort4*)(cwl + (size_t)d * 1024 + c4) = lo;
}

// ---------------------------------------------------------------------------
// k_prepw: words [i][1000 d][64 q] fp32 -> wT_hi/lo bf16 [i][64 q][1024 d]
// ---------------------------------------------------------------------------
__global__ __launch_bounds__(256) void k_prepw(
    const float* __restrict__ words, u16* __restrict__ wth, u16* __restrict__ wtl)
{
    int i = blockIdx.x >> 4, dt = blockIdx.x & 15;
    const float* src = words + (size_t)i * D_DIM * Q_DIM;
    __shared__ u16 Th[64][72], Tl[64][72];
    int tid = threadIdx.x;
    #pragma unroll
    for (int rep = 0; rep < 4; rep++) {
        int idx = tid + rep * 256;
        int dl = idx >> 4, q4 = (idx & 15) * 4;
        int d = dt * 64 + dl;
        float4 v = make_float4(0.f, 0.f, 0.f, 0.f);
        if (d < D_DIM) v = *(const float4*)(src + (size_t)d * Q_DIM + q4);
        float a[4] = {v.x, v.y, v.z, v.w};
        #pragma unroll
        for (int jj = 0; jj < 4; jj++) {
            u16 hh = f2b(a[jj]);
            Th[dl][q4 + jj] = hh;
            Tl[dl][q4 + jj] = f2b(a[jj] - b2f(hh));
        }
    }
    __syncthreads();
    #pragma unroll
    for (int rep = 0; rep < 2; rep++) {
        int idx = tid + rep * 256;
        int q = idx >> 3, c8 = idx & 7;
        bf16x8 vh, vl;
        #pragma unroll
        for (int jj = 0; jj < 8; jj++) { vh[jj] = (short)Th[c8 * 8 + jj][q]; vl[jj] = (short)Tl[c8 * 8 + jj][q]; }
        size_t doff = (size_t)i * 65536 + (size_t)q * 1024 + dt * 64 + c8 * 8;
        *(bf16x8*)(wth + doff) = vh;
        *(bf16x8*)(wtl + doff) = vl;
    }
}

// ---------------------------------------------------------------------------
// k_prep: T[e][d] = bf16(W[d][e]); [1024][1024], zero-padded. (for wl AND wg)
// ---------------------------------------------------------------------------
__global__ __launch_bounds__(256) void k_prep(const float* __restrict__ wl, u16* __restrict__ wlT)
{
    __shared__ float t[64][65];
    int bd = blockIdx.x & 15, be = blockIdx.x >> 4;
    int tx = threadIdx.x & 15, ty = threadIdx.x >> 4;
    #pragma unroll
    for (int rr = 0; rr < 4; rr++) {
        int r = ty * 4 + rr;
        int d = bd * 64 + r;
        int e4 = be * 64 + tx * 4;
        float v0 = 0.f, v1 = 0.f, v2 = 0.f, v3 = 0.f;
        if (d < D_DIM) {
            if (e4 + 3 < D_DIM) {
                float4 v = *reinterpret_cast<const float4*>(wl + (size_t)d * D_DIM + e4);
                v0 = v.x; v1 = v.y; v2 = v.z; v3 = v.w;
            } else {
                if (e4 + 0 < D_DIM) v0 = wl[(size_t)d * D_DIM + e4 + 0];
                if (e4 + 1 < D_DIM) v1 = wl[(size_t)d * D_DIM + e4 + 1];
                if (e4 + 2 < D_DIM) v2 = wl[(size_t)d * D_DIM + e4 + 2];
                if (e4 + 3 < D_DIM) v3 = wl[(size_t)d * D_DIM + e4 + 3];
            }
        }
        t[r][tx * 4 + 0] = v0; t[r][tx * 4 + 1] = v1;
        t[r][tx * 4 + 2] = v2; t[r][tx * 4 + 3] = v3;
    }
    __syncthreads();
    #pragma unroll
    for (int rr = 0; rr < 4; rr++) {
        int r2 = ty * 4 + rr;
        int e = be * 64 + r2;
        int d0 = bd * 64 + tx * 4;
        ushort4 h;
        h.x = f2b(t[tx * 4 + 0][r2]); h.y = f2b(t[tx * 4 + 1][r2]);
        h.z = f2b(t[tx * 4 + 2][r2]); h.w = f2b(t[tx * 4 + 3][r2]);
        *reinterpret_cast<ushort4*>(wlT + (size_t)e * 1024 + d0) = h;
    }
}

// ---------------------------------------------------------------------------
// k_convG: img = featT . cw^T (split-bf16 3-pass) + cb.  BK=32, swizzled,
// dbuf prefetch.  Epilogue writes img_hi (d-major) AND imgT_hi/lo (s-major,
// via LDS bounce).  qt loop MUST stay unrolled (rule #20, R9 lesson).
// grid 256 (XCD-grouped), 512 thr.
// ---------------------------------------------------------------------------
__global__ __launch_bounds__(512) void k_convG(
    const u16* __restrict__ fT_hi, const u16* __restrict__ fT_lo,
    const u16* __restrict__ cwh, const u16* __restrict__ cwl,
    const float* __restrict__ cb,
    u16* __restrict__ img_hi, u16* __restrict__ imgT_hi, u16* __restrict__ imgT_lo)
{
    const int bid0 = blockIdx.x;
    const int bid = (bid0 & 7) * 32 + (bid0 >> 3);   // XCD-grouped (256%8==0)
    const int mblk = bid >> 2, nt = bid & 3;
    const int m0 = mblk * 256, n0 = nt * 256;

    __shared__ char LDS[131072] __attribute__((aligned(16)));
    __shared__ float cbS[256];

    const int tid = threadIdx.x;
    const int wid = tid >> 6, lane = tid & 63;
    const int wr = wid >> 2, wc = wid & 3;
    const int l15 = lane & 15, l4 = lane >> 4;
    const int sw = (l15 >> 1) & 3;

    if (tid < 256) {
        int d = n0 + tid;
        cbS[tid] = (d < D_DIM) ? cb[d] : 0.f;
    }

    auto stage = [&](int buf, int k0) {
        char* base = LDS + buf * 65536;
        #pragma unroll
        for (int rep = 0; rep < 2; rep++) {
            int idx = tid + rep * 512;
            int row = idx >> 2, slot = idx & 3;
            int kb = (slot ^ ((row >> 1) & 3)) * 16;
            size_t ao = (size_t)(m0 + row) * 2048 + (size_t)k0 * 2 + kb;
            size_t bo = (size_t)(n0 + row) * 2048 + (size_t)k0 * 2 + kb;
            GLOAD(base + idx * 16, (const char*)fT_hi + ao);
            GLOAD(base + 16384 + idx * 16, (const char*)fT_lo + ao);
            GLOAD(base + 32768 + idx * 16, (const char*)cwh + bo);
            GLOAD(base + 49152 + idx * 16, (const char*)cwl + bo);
        }
    };

    f32x4 acc[8][4] = {};

    stage(0, 0);
    __syncthreads();
    int cur = 0;
    for (int k0 = 0; k0 < 1024; k0 += 32) {
        if (k0 + 32 < 1024) stage(cur ^ 1, k0 + 32);
        const char* Ah = LDS + cur * 65536;
        const char* Alo = Ah + 16384;
        const char* Bh = Ah + 32768;
        const char* Blo = Ah + 49152;
        bf16x8 ah[8], bh[4];
        #pragma unroll
        for (int mf = 0; mf < 8; mf++)
            ah[mf] = *(const bf16x8*)(Ah + (wr * 128 + mf * 16 + l15) * 64 + ((l4 ^ sw) * 16));
        #pragma unroll
        for (int nf = 0; nf < 4; nf++)
            bh[nf] = *(const bf16x8*)(Bh + (wc * 64 + nf * 16 + l15) * 64 + ((l4 ^ sw) * 16));
        #pragma unroll
        for (int mf = 0; mf < 8; mf++)
            #pragma unroll
            for (int nf = 0; nf < 4; nf++)
                acc[mf][nf] = __builtin_amdgcn_mfma_f32_16x16x32_bf16(ah[mf], bh[nf], acc[mf][nf], 0, 0, 0);
        #pragma unroll
        for (int mf = 0; mf < 8; mf++) {
            bf16x8 al = *(const bf16x8*)(Alo + (wr * 128 + mf * 16 + l15) * 64 + ((l4 ^ sw) * 16));
            #pragma unroll
            for (int nf = 0; nf < 4; nf++)
                acc[mf][nf] = __builtin_amdgcn_mfma_f32_16x16x32_bf16(al, bh[nf], acc[mf][nf], 0, 0, 0);
        }
        #pragma unroll
        for (int nf = 0; nf < 4; nf++) {
            bf16x8 bl = *(const bf16x8*)(Blo + (wc * 64 + nf * 16 + l15) * 64 + ((l4 ^ sw) * 16));
            #pragma unroll
            for (int mf = 0; mf < 8; mf++)
                acc[mf][nf] = __builtin_amdgcn_mfma_f32_16x16x32_bf16(ah[mf], bl, acc[mf][nf], 0, 0, 0);
        }
        __syncthreads();
        cur ^= 1;
    }
    const int b = m0 >> 9;
    const int sbase = m0 & 511;
    // img_hi (d-major) for k_wctx
    #pragma unroll
    for (int mf = 0; mf < 8; mf++) {
        int srow = sbase + wr * 128 + mf * 16 + l4 * 4;
        #pragma unroll
        for (int nf = 0; nf < 4; nf++) {
            int dcol = n0 + wc * 64 + nf * 16 + l15;
            float bias = cbS[wc * 64 + nf * 16 + l15];
            ushort4 h4;
            u16* ph = (u16*)&h4;
            #pragma unroll
            for (int r = 0; r < 4; r++)
                ph[r] = f2b(acc[mf][nf][r] + bias);
            *(ushort4*)(img_hi + ((size_t)b * 1024 + dcol) * 512 + srow) = h4;
        }
    }
    // imgT_hi/lo (s-major) via LDS bounce, 4 quarters of 64 s-rows x 256 d
    u16* Thi = (u16*)LDS;
    u16* Tlo = (u16*)(LDS + 33792);   // 64*264*2 = 33792 each
    #pragma unroll   // REQUIRED: keeps mf = (qt&1)*4+mm compile-time (rule #20)
    for (int qt = 0; qt < 4; qt++) {
        __syncthreads();
        if (wr == (qt >> 1)) {
            #pragma unroll
            for (int mm = 0; mm < 4; mm++) {
                int mf = (qt & 1) * 4 + mm;
                int sq = mm * 16 + l4 * 4;
                #pragma unroll
                for (int nf = 0; nf < 4; nf++) {
                    int dcol = wc * 64 + nf * 16 + l15;
                    float bias = cbS[dcol];
                    #pragma unroll
                    for (int r = 0; r < 4; r++) {
                        float v = acc[mf][nf][r] + bias;
                        u16 hh = f2b(v);
                        Thi[(sq + r) * 264 + dcol] = hh;
                        Tlo[(sq + r) * 264 + dcol] = f2b(v - b2f(hh));
                    }
                }
            }
        }
        __syncthreads();
        #pragma unroll
        for (int rep = 0; rep < 4; rep++) {
            int g = tid + rep * 512;
            int s = g >> 5, d8 = (g & 31) * 8;
            size_t go = ((size_t)b * 512 + sbase + qt * 64 + s) * 1024 + n0 + d8;
            *(bf16x8*)(imgT_hi + go) = *(const bf16x8*)(&Thi[s * 264 + d8]);
            *(bf16x8*)(imgT_lo + go) = *(const bf16x8*)(&Tlo[s * 264 + d8]);
        }
    }
}

// ---------------------------------------------------------------------------
// k_logits: per b: C[iq][s] = wT . imgT^T (3-pass split), softmax over q,
// U -> global, Zp partials, diag u -> out.  BK=32, swizzled, dbuf prefetch,
// XCD-grouped (all 16 blocks of a b on one XCD).
// ---------------------------------------------------------------------------
__global__ __launch_bounds__(512) void k_logits(
    const u16* __restrict__ wTh, const u16* __restrict__ wTl,
    const u16* __restrict__ iTh, const u16* __restrict__ iTl,
    u16* __restrict__ U, float* __restrict__ Zp, float* __restrict__ out)
{
    const int bid0 = blockIdx.x;
    const int bid = (bid0 & 7) * 64 + (bid0 >> 3);   // XCD-grouped (512%8==0)
    const int b = bid >> 4, mt = (bid >> 1) & 7, nt = bid & 1;
    const int m0 = mt * 256, n0 = nt * 256;

    __shared__ char LDS[131072] __attribute__((aligned(16)));

    const int tid = threadIdx.x;
    const int wid = tid >> 6, lane = tid & 63;
    const int wr = wid >> 2, wc = wid & 3;
    const int l15 = lane & 15, l4 = lane >> 4;
    const int sw = (l15 >> 1) & 3;

    auto stage = [&](int buf, int k0) {
        char* base = LDS + buf * 65536;
        #pragma unroll
        for (int rep = 0; rep < 2; rep++) {
            int idx = tid + rep * 512;
            int row = idx >> 2, slot = idx & 3;
            int kb = (slot ^ ((row >> 1) & 3)) * 16;
            size_t ao = (size_t)(m0 + row) * 2048 + (size_t)k0 * 2 + kb;
            size_t bo = ((size_t)b * 512 + n0 + row) * 2048 + (size_t)k0 * 2 + kb;
            GLOAD(base + idx * 16, (const char*)wTh + ao);
            GLOAD(base + 16384 + idx * 16, (const char*)wTl + ao);
            GLOAD(base + 32768 + idx * 16, (const char*)iTh + bo);
            GLOAD(base + 49152 + idx * 16, (const char*)iTl + bo);
        }
    };

    f32x4 acc[8][4] = {};

    stage(0, 0);
    __syncthreads();
    int cur = 0;
    for (int k0 = 0; k0 < 1024; k0 += 32) {
        if (k0 + 32 < 1024) stage(cur ^ 1, k0 + 32);
        const char* Ah = LDS + cur * 65536;
        const char* Alo = Ah + 16384;
        const char* Bh = Ah + 32768;
        const char* Blo = Ah + 49152;
        bf16x8 ah[8], bh[4];
        #pragma unroll
        for (int mf = 0; mf < 8; mf++)
            ah[mf] = *(const bf16x8*)(Ah + (wr * 128 + mf * 16 + l15) * 64 + ((l4 ^ sw) * 16));
        #pragma unroll
        for (int nf = 0; nf < 4; nf++)
            bh[nf] = *(const bf16x8*)(Bh + (wc * 64 + nf * 16 + l15) * 64 + ((l4 ^ sw) * 16));
        #pragma unroll
        for (int mf = 0; mf < 8; mf++)
            #pragma unroll
            for (int nf = 0; nf < 4; nf++)
                acc[mf][nf] = __builtin_amdgcn_mfma_f32_16x16x32_bf16(ah[mf], bh[nf], acc[mf][nf], 0, 0, 0);
        #pragma unroll
        for (int mf = 0; mf < 8; mf++) {
            bf16x8 al = *(const bf16x8*)(Alo + (wr * 128 + mf * 16 + l15) * 64 + ((l4 ^ sw) * 16));
            #pragma unroll
            for (int nf = 0; nf < 4; nf++)
                acc[mf][nf] = __builtin_amdgcn_mfma_f32_16x16x32_bf16(al, bh[nf], acc[mf][nf], 0, 0, 0);
        }
        #pragma unroll
        for (int nf = 0; nf < 4; nf++) {
            bf16x8 bl = *(const bf16x8*)(Blo + (wc * 64 + nf * 16 + l15) * 64 + ((l4 ^ sw) * 16));
            #pragma unroll
            for (int mf = 0; mf < 8; mf++)
                acc[mf][nf] = __builtin_amdgcn_mfma_f32_16x16x32_bf16(ah[mf], bl, acc[mf][nf], 0, 0, 0);
        }
        __syncthreads();
        cur ^= 1;
    }

    float zacc[8][4] = {};
    #pragma unroll
    for (int il = 0; il < 2; il++) {
        int i_glob = mt * 4 + wr * 2 + il;
        bool diag = (i_glob == b);
        #pragma unroll
        for (int nf = 0; nf < 4; nf++) {
            int scol = n0 + wc * 64 + nf * 16 + l15;
            float m = -3.4e38f;
            #pragma unroll
            for (int mm = 0; mm < 4; mm++)
                #pragma unroll
                for (int r = 0; r < 4; r++)
                    m = fmaxf(m, acc[il * 4 + mm][nf][r]);
            m = fmaxf(m, __shfl_xor(m, 16));
            m = fmaxf(m, __shfl_xor(m, 32));
            float e[16], sum = 0.f;
            #pragma unroll
            for (int mm = 0; mm < 4; mm++)
                #pragma unroll
                for (int r = 0; r < 4; r++) {
                    float ev = __expf(acc[il * 4 + mm][nf][r] - m);
                    e[mm * 4 + r] = ev; sum += ev;
                }
            sum += __shfl_xor(sum, 16);
            sum += __shfl_xor(sum, 32);
            float inv = 1.f / sum;
            #pragma unroll
            for (int mm = 0; mm < 4; mm++)
                #pragma unroll
                for (int r = 0; r < 4; r++) {
                    float u = __expf(4.f * e[mm * 4 + r] * inv);   // in [1, e^4]
                    u16 ub = f2b(u);
                    zacc[il * 4 + mm][r] += b2f(ub);
                    int iqrow = m0 + wr * 128 + (il * 4 + mm) * 16 + l4 * 4 + r;
                    U[((size_t)b * 2048 + iqrow) * 512 + scol] = ub;
                    if (diag) {
                        int q = iqrow & 63;
                        out[1024 + ((size_t)i_glob * 64 + q) * 512 + scol] = u;
                    }
                }
        }
    }
    #pragma unroll
    for (int mf = 0; mf < 8; mf++)
        #pragma unroll
        for (int r = 0; r < 4; r++) {
            float z = zacc[mf][r];
            z += __shfl_xor(z, 1); z += __shfl_xor(z, 2);
            z += __shfl_xor(z, 4); z += __shfl_xor(z, 8);
            if (l15 == 0) {
                int iqrow = m0 + wr * 128 + mf * 16 + l4 * 4 + r;
                Zp[((size_t)b * 2048 + iqrow) * 8 + nt * 4 + wc] = z;
            }
        }
}

// k_zred: invZf[gi] = 1 / sum of 8 Zp partials
__global__ __launch_bounds__(256) void k_zred(const float* __restrict__ Zp, float* __restrict__ invZf)
{
    int gi = blockIdx.x * 256 + threadIdx.x;
    float4 z0 = *(const float4*)(Zp + (size_t)gi * 8);
    float4 z1 = *(const float4*)(Zp + (size_t)gi * 8 + 4);
    invZf[gi] = 1.f / (z0.x + z0.y + z0.z + z0.w + z1.x + z1.y + z1.z + z1.w);
}

// normalize att_maps rows in place. 32 blocks.
__global__ __launch_bounds__(256) void k_attmap2(float* __restrict__ out)
{
    const int i = blockIdx.x;
    float* am = out + 1024 + (size_t)i * Q_DIM * S_DIM;
    int q = threadIdx.x >> 2, ch = threadIdx.x & 3;
    float s = 0.f;
    for (int ss = ch * 128; ss < ch * 128 + 128; ss++) s += am[(size_t)q * S_DIM + ss];
    s += __shfl_xor(s, 1);
    s += __shfl_xor(s, 2);
    float iz = 1.f / s;
    for (int ss = ch * 128; ss < ch * 128 + 128; ss++) am[(size_t)q * S_DIM + ss] *= iz;
}

// ---------------------------------------------------------------------------
// k_wctx: per b: C[d][iq] = img_hi . U^T, K=512, BK=32 (LDS 66KB -> 2
// blocks/CU for cross-block latency hiding), swizzled, dbuf prefetch,
// XCD-grouped.  Epilogue: v = acc*invZ*(wThi+wTlo) -> vbuf; ssq.
// ---------------------------------------------------------------------------
__global__ __launch_bounds__(512) void k_wctx(
    const u16* __restrict__ img_hi, const u16* __restrict__ U,
    const float* __restrict__ invZf,
    const u16* __restrict__ wTh, const u16* __restrict__ wTl,
    u16* __restrict__ vbuf, float* __restrict__ ssqp)
{
    const int bid0 = blockIdx.x;
    const int bid = (bid0 & 7) * 128 + (bid0 >> 3);   // XCD-grouped (1024%8==0)
    const int b = bid >> 5, mt = (bid >> 3) & 3, nt = bid & 7;
    const int m0 = mt * 256, n0 = nt * 256;

    __shared__ char LDS[65536] __attribute__((aligned(16)));   // 2buf x {A 16K, B 16K}
    __shared__ float izS[256];

    const int tid = threadIdx.x;
    const int wid = tid >> 6, lane = tid & 63;
    const int wr = wid >> 2, wc = wid & 3;
    const int l15 = lane & 15, l4 = lane >> 4;
    const int sw = (l15 >> 1) & 3;

    if (tid < 256) izS[tid] = invZf[b * 2048 + n0 + tid];

    auto stage = [&](int buf, int k0) {
        char* base = LDS + buf * 32768;
        #pragma unroll
        for (int rep = 0; rep < 2; rep++) {
            int idx = tid + rep * 512;
            int row = idx >> 2, slot = idx & 3;
            int kb = (slot ^ ((row >> 1) & 3)) * 16;
            GLOAD(base + idx * 16, (const char*)img_hi + ((size_t)b * 1024 + m0 + row) * 1024 + (size_t)k0 * 2 + kb);
            GLOAD(base + 16384 + idx * 16, (const char*)U + ((size_t)b * 2048 + n0 + row) * 1024 + (size_t)k0 * 2 + kb);
        }
    };

    f32x4 acc[8][4] = {};

    stage(0, 0);
    __syncthreads();
    int cur = 0;
    for (int k0 = 0; k0 < 512; k0 += 32) {
        if (k0 + 32 < 512) stage(cur ^ 1, k0 + 32);
        const char* At = LDS + cur * 32768;
        const char* Bt = At + 16384;
        bf16x8 a[8], bb[4];
        #pragma unroll
        for (int mf = 0; mf < 8; mf++)
            a[mf] = *(const bf16x8*)(At + (wr * 128 + mf * 16 + l15) * 64 + ((l4 ^ sw) * 16));
        #pragma unroll
        for (int nf = 0; nf < 4; nf++)
            bb[nf] = *(const bf16x8*)(Bt + (wc * 64 + nf * 16 + l15) * 64 + ((l4 ^ sw) * 16));
        #pragma unroll
        for (int mf = 0; mf < 8; mf++)
            #pragma unroll
            for (int nf = 0; nf < 4; nf++)
                acc[mf][nf] = __builtin_amdgcn_mfma_f32_16x16x32_bf16(a[mf], bb[nf], acc[mf][nf], 0, 0, 0);
        __syncthreads();
        cur ^= 1;
    }

    #pragma unroll
    for (int nf = 0; nf < 4; nf++) {
        int col = wc * 64 + nf * 16 + l15;
        int iq = n0 + col;
        float iz = izS[col];
        size_t wtoff = (size_t)iq * 1024;
        float s_nf = 0.f;
        #pragma unroll
        for (int mf = 0; mf < 8; mf++) {
            int d0 = m0 + wr * 128 + mf * 16 + l4 * 4;
            ushort4 wh = *(const ushort4*)(wTh + wtoff + d0);
            ushort4 wl = *(const ushort4*)(wTl + wtoff + d0);
            const u16* pwh = (const u16*)&wh;
            const u16* pwl = (const u16*)&wl;
            ushort4 vo;
            u16* pv = (u16*)&vo;
            #pragma unroll
            for (int r = 0; r < 4; r++) {
                float wv = b2f(pwh[r]) + b2f(pwl[r]);
                float v = acc[mf][nf][r] * iz * wv;
                s_nf = fmaf(v, v, s_nf);
                pv[r] = f2b(v);
            }
            *(ushort4*)(vbuf + ((size_t)b * 2048 + iq) * 1024 + d0) = vo;
        }
        s_nf += __shfl_xor(s_nf, 16);
        s_nf += __shfl_xor(s_nf, 32);
        if (l4 == 0) ssqp[((size_t)b * 2048 + iq) * 4 + mt] = s_nf;
    }
}

// ---------------------------------------------------------------------------
// k_post: per pair: invn from ssqp; simave_bf16[pair][1024] = mean_q v*invn
// ---------------------------------------------------------------------------
__global__ __launch_bounds__(256) void k_post(
    const u16* __restrict__ vbuf, const float* __restrict__ ssqp,
    float* __restrict__ invn_ws, u16* __restrict__ simave_bf)
{
    const int pair = blockIdx.x;
    __shared__ float invnS[64];
    const int tid = threadIdx.x;
    if (tid < 64) {
        size_t o = ((size_t)pair * 64 + tid) * 4;
        float s = ssqp[o] + ssqp[o + 1] + ssqp[o + 2] + ssqp[o + 3];
        float n = 1.f / (sqrtf(s) + 1e-8f);
        invnS[tid] = n;
        invn_ws[pair * 64 + tid] = n;
    }
    __syncthreads();
    int d0 = tid * 4;
    ushort4 o4 = make_ushort4(0, 0, 0, 0);
    if (d0 < D_DIM) {
        float a0 = 0.f, a1 = 0.f, a2 = 0.f, a3 = 0.f;
        const u16* vb = vbuf + (size_t)pair * 65536;
        for (int q = 0; q < 64; q++) {
            float n = invnS[q];
            ushort4 v = *(const ushort4*)(vb + q * 1024 + d0);
            a0 = fmaf(b2f(v.x), n, a0); a1 = fmaf(b2f(v.y), n, a1);
            a2 = fmaf(b2f(v.z), n, a2); a3 = fmaf(b2f(v.w), n, a3);
        }
        o4.x = f2b(a0 * (1.f / 64.f)); o4.y = f2b(a1 * (1.f / 64.f));
        o4.z = f2b(a2 * (1.f / 64.f)); o4.w = f2b(a3 * (1.f / 64.f));
    }
    *(ushort4*)(simave_bf + (size_t)pair * 1024 + d0) = o4;
}

// ---------------------------------------------------------------------------
// k_g2M: g2[p][e] = tanh(simave . wg + bg) * wc  via bf16 MFMA.
// 128x128 tiles, grid 64, 256 thr, dbuf.
// ---------------------------------------------------------------------------
__global__ __launch_bounds__(256) void k_g2M(
    const u16* __restrict__ simave_bf, const u16* __restrict__ wgT,
    const float* __restrict__ bg, const float* __restrict__ wc,
    float* __restrict__ g2)
{
    const int mt = blockIdx.x >> 3, nt = blockIdx.x & 7;
    const int m0 = mt * 128, n0 = nt * 128;

    __shared__ char LDS[65536] __attribute__((aligned(16)));  // 2 x {A 16K, B 16K}
    __shared__ float bgS[128], wcS[128];

    const int tid = threadIdx.x;
    const int wid = tid >> 6, lane = tid & 63;
    const int wr = wid >> 1, wc_ = wid & 1;
    const int l15 = lane & 15, l4 = lane >> 4;
    const int sw = l15 & 7;

    if (tid < 128) {
        int e = n0 + tid;
        bgS[tid] = (e < D_DIM) ? bg[e] : 0.f;
        wcS[tid] = (e < D_DIM) ? wc[e] : 0.f;
    }

    auto stage = [&](int buf, int k0) {
        char* base = LDS + buf * 32768;
        #pragma unroll
        for (int rep = 0; rep < 4; rep++) {
            int idx = tid + rep * 256;
            int row = idx >> 3, slot = idx & 7;
            int kb = (slot ^ (row & 7)) * 16;
            GLOAD(base + idx * 16, (const char*)simave_bf + (size_t)(m0 + row) * 2048 + (size_t)k0 * 2 + kb);
            GLOAD(base + 16384 + idx * 16, (const char*)wgT + (size_t)(n0 + row) * 2048 + (size_t)k0 * 2 + kb);
        }
    };

    f32x4 acc[4][4] = {};

    stage(0, 0);
    __syncthreads();
    int cur = 0;
    for (int k0 = 0; k0 < 1024; k0 += 64) {
        if (k0 + 64 < 1024) stage(cur ^ 1, k0 + 64);
        const char* Al = LDS + cur * 32768;
        const char* Bl = Al + 16384;
        #pragma unroll
        for (int kf = 0; kf < 2; kf++) {
            bf16x8 a[4], bb[4];
            #pragma unroll
            for (int mf = 0; mf < 4; mf++)
                a[mf] = *(const bf16x8*)(Al + (wr * 64 + mf * 16 + l15) * 128 + (((kf * 4 + l4) ^ sw) * 16));
            #pragma unroll
            for (int nf = 0; nf < 4; nf++)
                bb[nf] = *(const bf16x8*)(Bl + (wc_ * 64 + nf * 16 + l15) * 128 + (((kf * 4 + l4) ^ sw) * 16));
            #pragma unroll
            for (int mf = 0; mf < 4; mf++)
                #pragma unroll
                for (int nf = 0; nf < 4; nf++)
                    acc[mf][nf] = __builtin_amdgcn_mfma_f32_16x16x32_bf16(a[mf], bb[nf], acc[mf][nf], 0, 0, 0);
        }
        __syncthreads();
        cur ^= 1;
    }

    #pragma unroll
    for (int mf = 0; mf < 4; mf++) {
        int p = m0 + wr * 64 + mf * 16 + l4 * 4;
        #pragma unroll
        for (int nf = 0; nf < 4; nf++) {
            int cl = wc_ * 64 + nf * 16 + l15;
            float bgv = bgS[cl], wcv = wcS[cl];
            #pragma unroll
            for (int r = 0; r < 4; r++)
                g2[(size_t)(p + r) * 1024 + n0 + cl] = ftanh(acc[mf][nf][r] + bgv) * wcv;
        }
    }
}

// ---------------------------------------------------------------------------
// k_saG: flat GEMM M=65536, N=1024, K=1024.  BK=32 (LDS 70KB -> 2 blocks/CU
// for cross-block latency hiding), swizzled, dbuf prefetch, nt-fast + XCD
// block swizzle.
// ---------------------------------------------------------------------------
__global__ __launch_bounds__(512) void k_saG(
    const u16* __restrict__ vbuf, const u16* __restrict__ wlT,
    const float* __restrict__ invn_ws, const float* __restrict__ g2_ws,
    const float* __restrict__ bl, float* __restrict__ wspart)
{
    const int bid = blockIdx.x;
    const int wg = (bid & 7) * 128 + (bid >> 3);
    const int mt = wg >> 2, nt = wg & 3;
    const int m0 = mt * 256, n0 = nt * 256;

    __shared__ char LDS[65536] __attribute__((aligned(16)));   // 2buf x {A 16K, B 16K}
    __shared__ float invnS[256];
    __shared__ float blS[256];
    __shared__ float g2S[4 * 256];

    const int tid = threadIdx.x;
    const int wid = tid >> 6, lane = tid & 63;
    const int wr = wid >> 2, wc = wid & 3;
    const int l15 = lane & 15, l4 = lane >> 4;
    const int sw = (l15 >> 1) & 3;

    if (tid < 256) {
        invnS[tid] = invn_ws[m0 + tid];
        int e = n0 + tid;
        blS[tid] = (e < D_DIM) ? bl[e] : 0.f;
    }
    #pragma unroll
    for (int rep = 0; rep < 2; rep++) {
        int idx = tid + rep * 512;
        int p = idx >> 8, el = idx & 255;
        g2S[idx] = g2_ws[(size_t)((m0 >> 6) + p) * 1024 + n0 + el];
    }

    auto stage = [&](int buf, int k0) {
        char* base = LDS + buf * 32768;
        #pragma unroll
        for (int rep = 0; rep < 2; rep++) {
            int idx = tid + rep * 512;
            int row = idx >> 2, slot = idx & 3;
            int kb = (slot ^ ((row >> 1) & 3)) * 16;
            GLOAD(base + idx * 16, (const char*)vbuf + (size_t)(m0 + row) * 2048 + (size_t)k0 * 2 + kb);
            GLOAD(base + 16384 + idx * 16, (const char*)wlT + (size_t)(n0 + row) * 2048 + (size_t)k0 * 2 + kb);
        }
    };

    f32x4 acc[8][4] = {};

    stage(0, 0);
    __syncthreads();
    int cur = 0;
    for (int k0 = 0; k0 < 1024; k0 += 32) {
        if (k0 + 32 < 1024) stage(cur ^ 1, k0 + 32);
        const char* Al = LDS + cur * 32768;
        const char* Bl = Al + 16384;
        bf16x8 a[8], bb[4];
        #pragma unroll
        for (int mf = 0; mf < 8; mf++)
            a[mf] = *(const bf16x8*)(Al + (wr * 128 + mf * 16 + l15) * 64 + ((l4 ^ sw) * 16));
        #pragma unroll
        for (int nf = 0; nf < 4; nf++)
            bb[nf] = *(const bf16x8*)(Bl + (wc * 64 + nf * 16 + l15) * 64 + ((l4 ^ sw) * 16));
        #pragma unroll
        for (int mf = 0; mf < 8; mf++)
            #pragma unroll
            for (int nf = 0; nf < 4; nf++)
                acc[mf][nf] = __builtin_amdgcn_mfma_f32_16x16x32_bf16(a[mf], bb[nf], acc[mf][nf], 0, 0, 0);
        __syncthreads();
        cur ^= 1;
    }

    #pragma unroll
    for (int mf = 0; mf < 8; mf++) {
        int mrow = wr * 128 + mf * 16 + l4 * 4;
        #pragma unroll
        for (int r = 0; r < 4; r++) {
            float inv = invnS[mrow + r];
            int p = (mrow + r) >> 6;
            float s = 0.f;
            #pragma unroll
            for (int nf = 0; nf < 4; nf++) {
                int el = wc * 64 + nf * 16 + l15;
                float x = acc[mf][nf][r] * inv + blS[el];
                s += ftanh(x) * g2S[p * 256 + el];
            }
            s += __shfl_xor(s, 1);
            s += __shfl_xor(s, 2);
            s += __shfl_xor(s, 4);
            s += __shfl_xor(s, 8);
            if (l15 == 0)
                wspart[(size_t)(nt * 4 + wc) * 65536 + m0 + mrow + r] = s;
        }
    }
}

// ---------------------------------------------------------------------------
// k_sa2: per pair: w[q] -> softmax -> new_global -> l2norm -> sigmoid -> out
// ---------------------------------------------------------------------------
__global__ __launch_bounds__(256) void k_sa2(
    const float* __restrict__ wspart, const float* __restrict__ invn_ws,
    const u16* __restrict__ vbuf, const float* __restrict__ capw,
    const float* __restrict__ capb, float* __restrict__ out)
{
    const int pair = blockIdx.x;
    const u16* vb = vbuf + (size_t)pair * 65536;

    __shared__ float wiS[64];
    __shared__ float red[8];

    const int tid = threadIdx.x;

    if (tid < 64) {
        float x = 0.f;
        #pragma unroll
        for (int c = 0; c < 16; c++) x += wspart[(size_t)c * 65536 + pair * 64 + tid];
        float m = x;
        #pragma unroll
        for (int mk = 1; mk < 64; mk <<= 1) m = fmaxf(m, __shfl_xor(m, mk));
        float e = __expf(x - m);
        float Z = e;
        #pragma unroll
        for (int mk = 1; mk < 64; mk <<= 1) Z += __shfl_xor(Z, mk);
        wiS[tid] = (e / Z) * invn_ws[pair * 64 + tid];
    }
    __syncthreads();

    float s1 = 0.f, s2 = 0.f;
    int d0 = tid * 4;
    if (d0 < D_DIM) {
        float a0 = 0.f, a1 = 0.f, a2 = 0.f, a3 = 0.f;
        for (int q = 0; q < 64; q++) {
            float wq = wiS[q];
            ushort4 v = *(const ushort4*)(vb + q * 1024 + d0);
            a0 = fmaf(wq, b2f(v.x), a0); a1 = fmaf(wq, b2f(v.y), a1);
            a2 = fmaf(wq, b2f(v.z), a2); a3 = fmaf(wq, b2f(v.w), a3);
        }
        float4 cw4 = *(const float4*)(capw + d0);
        s1 = a0 * cw4.x + a1 * cw4.y + a2 * cw4.z + a3 * cw4.w;
        s2 = a0 * a0 + a1 * a1 + a2 * a2 + a3 * a3;
    }
    #pragma unroll
    for (int mk = 1; mk < 64; mk <<= 1) { s1 += __shfl_xor(s1, mk); s2 += __shfl_xor(s2, mk); }
    if ((tid & 63) == 0) { red[tid >> 6] = s1; red[4 + (tid >> 6)] = s2; }
    __syncthreads();
    if (tid == 0) {
        float S1 = red[0] + red[1] + red[2] + red[3];
        float S2 = red[4] + red[5] + red[6] + red[7];
        float val = S1 / (sqrtf(S2) + 1e-8f) + capb[0];
        out[pair] = 1.f / (1.f + __expf(-val));
    }
}

// ---------------------------------------------------------------------------
extern "C" void kernel_launch(void* const* d_in, const int* in_sizes, int n_in,
                              void* d_out, int out_size, void* d_ws, size_t ws_size,
                              hipStream_t stream)
{
    const float* feat_l = (const float*)d_in[0];
    const float* feat_f = (const float*)d_in[1];
    const float* words  = (const float*)d_in[2];
    const float* conv_w = (const float*)d_in[3];
    const float* conv_b = (const float*)d_in[4];
    const float* sa_wl  = (const float*)d_in[5];
    const float* sa_bl  = (const float*)d_in[6];
    const float* sa_wg  = (const float*)d_in[7];
    const float* sa_bg  = (const float*)d_in[8];
    const float* sa_wc  = (const float*)d_in[9];
    // d_in[10] = sa_bc: constant pre-softmax shift -> result-invariant
    const float* cap_w  = (const float*)d_in[11];
    const float* cap_b  = (const float*)d_in[12];
    float* out = (float*)d_out;

    char* ws = (char*)d_ws;
    // Overlay layout (bytes), peak 253,755,392:
    //   [0,134.2M): featT_hi@0, featT_lo@33.5M (prepf->convG);
    //               imgT_hi@67.1M, imgT_lo@100.7M (convG->logits); vbuf@0 (wctx->sa2)
    //   [134.2M,167.8M): img_hi (convG->wctx); wgT@134.2M (prep-late->g2M)
    //   [167.8M,234.9M): U@167.8M (logits->wctx); wspart@167.8M (saG->sa2)
    //   [234.9M,243.3M): wT_hi,wT_lo (prepw->wctx); simave_bf@234.9M (post->g2M)
    //   [243.3M,247.5M): cw_hi,cw_lo (prepcw->convG); then Zp, invZf, ssqp, invn
    //   [247.5M,249.6M): wlT ; [249.6M,253.76M): g2 fp32 [1024][1024]
    u16*   featT_hi  = (u16*)(ws);
    u16*   featT_lo  = (u16*)(ws + 33554432);
    u16*   imgT_hi   = (u16*)(ws + 67108864);
    u16*   imgT_lo   = (u16*)(ws + 100663296);
    u16*   vbuf      = (u16*)(ws);
    u16*   img_hi    = (u16*)(ws + 134217728);
    u16*   wgT       = (u16*)(ws + 134217728);
    u16*   U         = (u16*)(ws + 167772160);
    float* wspart    = (float*)(ws + 167772160);
    u16*   wT_hi     = (u16*)(ws + 234881024);
    u16*   simave_bf = (u16*)(ws + 234881024);
    u16*   wT_lo     = (u16*)(ws + 239075328);
    u16*   cw_hi     = (u16*)(ws + 243269632);
    float* Zp        = (float*)(ws + 243269632);
    u16*   cw_lo     = (u16*)(ws + 245366784);
    float* invZf     = (float*)(ws + 245366784);
    float* ssqp      = (float*)(ws + 245628928);
    float* invn      = (float*)(ws + 246677504);
    u16*   wlT       = (u16*)(ws + 247463936);
    float* g2        = (float*)(ws + 249561088);

    hipLaunchKernelGGL(k_prepf, dim3(4096), dim3(256), 0, stream,
                       feat_l, feat_f, featT_hi, featT_lo);
    hipLaunchKernelGGL(k_prepcw, dim3(1024), dim3(256), 0, stream,
                       conv_w, cw_hi, cw_lo);
    hipLaunchKernelGGL(k_prepw, dim3(512), dim3(256), 0, stream,
                       words, wT_hi, wT_lo);
    hipLaunchKernelGGL(k_prep, dim3(256), dim3(256), 0, stream, sa_wl, wlT);
    hipLaunchKernelGGL(k_convG, dim3(256), dim3(512), 0, stream,
                       featT_hi, featT_lo, cw_hi, cw_lo, conv_b,
                       img_hi, imgT_hi, imgT_lo);
    hipLaunchKernelGGL(k_logits, dim3(512), dim3(512), 0, stream,
                       wT_hi, wT_lo, imgT_hi, imgT_lo, U, Zp, out);
    hipLaunchKernelGGL(k_zred, dim3(256), dim3(256), 0, stream, Zp, invZf);
    hipLaunchKernelGGL(k_attmap2, dim3(32), dim3(256), 0, stream, out);
    hipLaunchKernelGGL(k_wctx, dim3(1024), dim3(512), 0, stream,
                       img_hi, U, invZf, wT_hi, wT_lo, vbuf, ssqp);
    hipLaunchKernelGGL(k_prep, dim3(256), dim3(256), 0, stream, sa_wg, wgT);
    hipLaunchKernelGGL(k_post, dim3(1024), dim3(256), 0, stream,
                       vbuf, ssqp, invn, simave_bf);
    hipLaunchKernelGGL(k_g2M, dim3(64), dim3(256), 0, stream,
                       simave_bf, wgT, sa_bg, sa_wc, g2);
    hipLaunchKernelGGL(k_saG, dim3(1024), dim3(512), 0, stream,
                       vbuf, wlT, invn, g2, sa_bl, wspart);
    hipLaunchKernelGGL(k_sa2, dim3(1024), dim3(256), 0, stream,
                       wspart, invn, vbuf, cap_w, cap_b, out);
}

// Round 12
// 671.852 us; speedup vs baseline: 1.0223x; 1.0223x over previous
//
#include <hip/hip_runtime.h>
#include <cstdint>

typedef unsigned short u16;
typedef unsigned int   u32;
typedef __attribute__((ext_vector_type(8))) short bf16x8;
typedef __attribute__((ext_vector_type(4))) float f32x4;

#define D_DIM 1000
#define C_IN  1024
#define HW    256
#define S_DIM 512
#define Q_DIM 64

__device__ __forceinline__ u16 f2b(float x) {
    u32 u = __builtin_bit_cast(u32, x);
    u32 r = (u + 0x7FFFu + ((u >> 16) & 1u)) >> 16;
    return (u16)r;
}
__device__ __forceinline__ float b2f(u16 h) {
    u32 u = ((u32)h) << 16;
    return __builtin_bit_cast(float, u);
}
__device__ __forceinline__ float ftanh(float x) {
    float e = __expf(2.f * x);
    return 1.f - 2.f / (e + 1.f);
}

#define GLOAD(ldsptr, gptr) \
    __builtin_amdgcn_global_load_lds( \
        (const __attribute__((address_space(1))) unsigned int*)(gptr), \
        (__attribute__((address_space(3))) unsigned int*)(ldsptr), 16, 0, 0)

// ---------------------------------------------------------------------------
// k_prepAll: grid-fused independent prep kernels (branch on blockIdx range,
// block-uniform). 5888 blocks, 256 thr.
//   [0,4096)     prepf : feat fp32 -> featT_hi/lo bf16 [b][512 s][1024 c]
//   [4096,5120)  prepcw: cw -> cw_hi/lo [1024][1024]
//   [5120,5632)  prepw : words -> wT_hi/lo [i][64 q][1024 d]
//   [5632,5888)  prep  : wl -> wlT [1024 e][1024 d]
// ---------------------------------------------------------------------------
__global__ __launch_bounds__(256) void k_prepAll(
    const float* __restrict__ feat_l, const float* __restrict__ feat_f,
    const float* __restrict__ cw, const float* __restrict__ words,
    const float* __restrict__ wl,
    u16* __restrict__ fT_hi, u16* __restrict__ fT_lo,
    u16* __restrict__ cwh, u16* __restrict__ cwl,
    u16* __restrict__ wth, u16* __restrict__ wtl,
    u16* __restrict__ wlT)
{
    __shared__ char SH[18432] __attribute__((aligned(16)));
    const int bid = blockIdx.x;
    const int tid = threadIdx.x;

    if (bid < 4096) {
        // ---- prepf
        float (*T)[65] = (float(*)[65])SH;   // 64*65*4 = 16640 B
        int ct = bid & 15, ht = (bid >> 4) & 3, half_ = (bid >> 6) & 1, b = bid >> 7;
        const float* src = (half_ ? feat_l : feat_f) + (size_t)b * C_IN * HW;
        {
            int cl = tid >> 2, h16 = (tid & 3) * 16;
            const float* p = src + (size_t)(ct * 64 + cl) * 256 + ht * 64 + h16;
            #pragma unroll
            for (int j = 0; j < 4; j++) {
                float4 v = *(const float4*)(p + j * 4);
                T[h16 + j * 4 + 0][cl] = v.x;
                T[h16 + j * 4 + 1][cl] = v.y;
                T[h16 + j * 4 + 2][cl] = v.z;
                T[h16 + j * 4 + 3][cl] = v.w;
            }
        }
        __syncthreads();
        {
            int hl = tid >> 2, c16 = (tid & 3) * 16;
            int srow = b * 512 + half_ * 256 + ht * 64 + hl;
            bf16x8 vh[2], vlo[2];
            #pragma unroll
            for (int g = 0; g < 2; g++)
                #pragma unroll
                for (int j = 0; j < 8; j++) {
                    float x = T[hl][c16 + g * 8 + j];
                    u16 hh = f2b(x);
                    vh[g][j] = (short)hh;
                    vlo[g][j] = (short)f2b(x - b2f(hh));
                }
            size_t o = (size_t)srow * 1024 + ct * 64 + c16;
            *(bf16x8*)(fT_hi + o) = vh[0];
            *(bf16x8*)(fT_hi + o + 8) = vh[1];
            *(bf16x8*)(fT_lo + o) = vlo[0];
            *(bf16x8*)(fT_lo + o + 8) = vlo[1];
        }
    } else if (bid < 5120) {
        // ---- prepcw
        int d = bid - 4096;
        int c4 = tid * 4;
        ushort4 h = make_ushort4(0, 0, 0, 0), lo = make_ushort4(0, 0, 0, 0);
        if (d < D_DIM) {
            float4 v = *(const float4*)(cw + (size_t)d * 1024 + c4);
            float a[4] = {v.x, v.y, v.z, v.w};
            u16* ph = (u16*)&h; u16* pl = (u16*)&lo;
            #pragma unroll
            for (int j = 0; j < 4; j++) {
                ph[j] = f2b(a[j]);
                pl[j] = f2b(a[j] - b2f(ph[j]));
            }
        }
        *(ushort4*)(cwh + (size_t)d * 1024 + c4) = h;
        *(ushort4*)(cwl + (size_t)d * 1024 + c4) = lo;
    } else if (bid < 5632) {
        // ---- prepw
        int lb = bid - 5120;
        int i = lb >> 4, dt = lb & 15;
        const float* src = words + (size_t)i * D_DIM * Q_DIM;
        u16 (*Th)[72] = (u16(*)[72])SH;            // 64*72*2 = 9216 B
        u16 (*Tl)[72] = (u16(*)[72])(SH + 9216);   // 9216 B
        #pragma unroll
        for (int rep = 0; rep < 4; rep++) {
            int idx = tid + rep * 256;
            int dl = idx >> 4, q4 = (idx & 15) * 4;
            int d = dt * 64 + dl;
            float4 v = make_float4(0.f, 0.f, 0.f, 0.f);
            if (d < D_DIM) v = *(const float4*)(src + (size_t)d * Q_DIM + q4);
            float a[4] = {v.x, v.y, v.z, v.w};
            #pragma unroll
            for (int jj = 0; jj < 4; jj++) {
                u16 hh = f2b(a[jj]);
                Th[dl][q4 + jj] = hh;
                Tl[dl][q4 + jj] = f2b(a[jj] - b2f(hh));
            }
        }
        __syncthreads();
        #pragma unroll
        for (int rep = 0; rep < 2; rep++) {
            int idx = tid + rep * 256;
            int q = idx >> 3, c8 = idx & 7;
            bf16x8 vh, vlo;
            #pragma unroll
            for (int jj = 0; jj < 8; jj++) { vh[jj] = (short)Th[c8 * 8 + jj][q]; vlo[jj] = (short)Tl[c8 * 8 + jj][q]; }
            size_t doff = (size_t)i * 65536 + (size_t)q * 1024 + dt * 64 + c8 * 8;
            *(bf16x8*)(wth + doff) = vh;
            *(bf16x8*)(wtl + doff) = vlo;
        }
    } else {
        // ---- prep (wl -> wlT)
        int lb = bid - 5632;
        float (*t)[65] = (float(*)[65])SH;   // 16640 B
        int bd = lb & 15, be = lb >> 4;
        int tx = tid & 15, ty = tid >> 4;
        #pragma unroll
        for (int rr = 0; rr < 4; rr++) {
            int r = ty * 4 + rr;
            int d = bd * 64 + r;
            int e4 = be * 64 + tx * 4;
            float v0 = 0.f, v1 = 0.f, v2 = 0.f, v3 = 0.f;
            if (d < D_DIM) {
                if (e4 + 3 < D_DIM) {
                    float4 v = *reinterpret_cast<const float4*>(wl + (size_t)d * D_DIM + e4);
                    v0 = v.x; v1 = v.y; v2 = v.z; v3 = v.w;
                } else {
                    if (e4 + 0 < D_DIM) v0 = wl[(size_t)d * D_DIM + e4 + 0];
                    if (e4 + 1 < D_DIM) v1 = wl[(size_t)d * D_DIM + e4 + 1];
                    if (e4 + 2 < D_DIM) v2 = wl[(size_t)d * D_DIM + e4 + 2];
                    if (e4 + 3 < D_DIM) v3 = wl[(size_t)d * D_DIM + e4 + 3];
                }
            }
            t[r][tx * 4 + 0] = v0; t[r][tx * 4 + 1] = v1;
            t[r][tx * 4 + 2] = v2; t[r][tx * 4 + 3] = v3;
        }
        __syncthreads();
        #pragma unroll
        for (int rr = 0; rr < 4; rr++) {
            int r2 = ty * 4 + rr;
            int e = be * 64 + r2;
            int d0 = bd * 64 + tx * 4;
            ushort4 h;
            h.x = f2b(t[tx * 4 + 0][r2]); h.y = f2b(t[tx * 4 + 1][r2]);
            h.z = f2b(t[tx * 4 + 2][r2]); h.w = f2b(t[tx * 4 + 3][r2]);
            *reinterpret_cast<ushort4*>(wlT + (size_t)e * 1024 + d0) = h;
        }
    }
}

// ---------------------------------------------------------------------------
// k_convG: img = featT . cw^T (split-bf16 3-pass) + cb.  BK=32, swizzled,
// dbuf prefetch.  Epilogue writes img_hi (d-major) AND imgT_hi/lo (s-major,
// via LDS bounce).  qt loop MUST stay unrolled (rule #20, R9 lesson).
// grid 256 (XCD-grouped), 512 thr.
// ---------------------------------------------------------------------------
__global__ __launch_bounds__(512) void k_convG(
    const u16* __restrict__ fT_hi, const u16* __restrict__ fT_lo,
    const u16* __restrict__ cwh, const u16* __restrict__ cwl,
    const float* __restrict__ cb,
    u16* __restrict__ img_hi, u16* __restrict__ imgT_hi, u16* __restrict__ imgT_lo)
{
    const int bid0 = blockIdx.x;
    const int bid = (bid0 & 7) * 32 + (bid0 >> 3);   // XCD-grouped (256%8==0)
    const int mblk = bid >> 2, nt = bid & 3;
    const int m0 = mblk * 256, n0 = nt * 256;

    __shared__ char LDS[131072] __attribute__((aligned(16)));
    __shared__ float cbS[256];

    const int tid = threadIdx.x;
    const int wid = tid >> 6, lane = tid & 63;
    const int wr = wid >> 2, wc = wid & 3;
    const int l15 = lane & 15, l4 = lane >> 4;
    const int sw = (l15 >> 1) & 3;

    if (tid < 256) {
        int d = n0 + tid;
        cbS[tid] = (d < D_DIM) ? cb[d] : 0.f;
    }

    auto stage = [&](int buf, int k0) {
        char* base = LDS + buf * 65536;
        #pragma unroll
        for (int rep = 0; rep < 2; rep++) {
            int idx = tid + rep * 512;
            int row = idx >> 2, slot = idx & 3;
            int kb = (slot ^ ((row >> 1) & 3)) * 16;
            size_t ao = (size_t)(m0 + row) * 2048 + (size_t)k0 * 2 + kb;
            size_t bo = (size_t)(n0 + row) * 2048 + (size_t)k0 * 2 + kb;
            GLOAD(base + idx * 16, (const char*)fT_hi + ao);
            GLOAD(base + 16384 + idx * 16, (const char*)fT_lo + ao);
            GLOAD(base + 32768 + idx * 16, (const char*)cwh + bo);
            GLOAD(base + 49152 + idx * 16, (const char*)cwl + bo);
        }
    };

    f32x4 acc[8][4] = {};

    stage(0, 0);
    __syncthreads();
    int cur = 0;
    for (int k0 = 0; k0 < 1024; k0 += 32) {
        if (k0 + 32 < 1024) stage(cur ^ 1, k0 + 32);
        const char* Ah = LDS + cur * 65536;
        const char* Alo = Ah + 16384;
        const char* Bh = Ah + 32768;
        const char* Blo = Ah + 49152;
        bf16x8 ah[8], bh[4];
        #pragma unroll
        for (int mf = 0; mf < 8; mf++)
            ah[mf] = *(const bf16x8*)(Ah + (wr * 128 + mf * 16 + l15) * 64 + ((l4 ^ sw) * 16));
        #pragma unroll
        for (int nf = 0; nf < 4; nf++)
            bh[nf] = *(const bf16x8*)(Bh + (wc * 64 + nf * 16 + l15) * 64 + ((l4 ^ sw) * 16));
        #pragma unroll
        for (int mf = 0; mf < 8; mf++)
            #pragma unroll
            for (int nf = 0; nf < 4; nf++)
                acc[mf][nf] = __builtin_amdgcn_mfma_f32_16x16x32_bf16(ah[mf], bh[nf], acc[mf][nf], 0, 0, 0);
        #pragma unroll
        for (int mf = 0; mf < 8; mf++) {
            bf16x8 al = *(const bf16x8*)(Alo + (wr * 128 + mf * 16 + l15) * 64 + ((l4 ^ sw) * 16));
            #pragma unroll
            for (int nf = 0; nf < 4; nf++)
                acc[mf][nf] = __builtin_amdgcn_mfma_f32_16x16x32_bf16(al, bh[nf], acc[mf][nf], 0, 0, 0);
        }
        #pragma unroll
        for (int nf = 0; nf < 4; nf++) {
            bf16x8 bl = *(const bf16x8*)(Blo + (wc * 64 + nf * 16 + l15) * 64 + ((l4 ^ sw) * 16));
            #pragma unroll
            for (int mf = 0; mf < 8; mf++)
                acc[mf][nf] = __builtin_amdgcn_mfma_f32_16x16x32_bf16(ah[mf], bl, acc[mf][nf], 0, 0, 0);
        }
        __syncthreads();
        cur ^= 1;
    }
    const int b = m0 >> 9;
    const int sbase = m0 & 511;
    // img_hi (d-major) for k_wctx
    #pragma unroll
    for (int mf = 0; mf < 8; mf++) {
        int srow = sbase + wr * 128 + mf * 16 + l4 * 4;
        #pragma unroll
        for (int nf = 0; nf < 4; nf++) {
            int dcol = n0 + wc * 64 + nf * 16 + l15;
            float bias = cbS[wc * 64 + nf * 16 + l15];
            ushort4 h4;
            u16* ph = (u16*)&h4;
            #pragma unroll
            for (int r = 0; r < 4; r++)
                ph[r] = f2b(acc[mf][nf][r] + bias);
            *(ushort4*)(img_hi + ((size_t)b * 1024 + dcol) * 512 + srow) = h4;
        }
    }
    // imgT_hi/lo (s-major) via LDS bounce, 4 quarters of 64 s-rows x 256 d
    u16* Thi = (u16*)LDS;
    u16* Tlo = (u16*)(LDS + 33792);   // 64*264*2 = 33792 each
    #pragma unroll   // REQUIRED: keeps mf = (qt&1)*4+mm compile-time (rule #20)
    for (int qt = 0; qt < 4; qt++) {
        __syncthreads();
        if (wr == (qt >> 1)) {
            #pragma unroll
            for (int mm = 0; mm < 4; mm++) {
                int mf = (qt & 1) * 4 + mm;
                int sq = mm * 16 + l4 * 4;
                #pragma unroll
                for (int nf = 0; nf < 4; nf++) {
                    int dcol = wc * 64 + nf * 16 + l15;
                    float bias = cbS[dcol];
                    #pragma unroll
                    for (int r = 0; r < 4; r++) {
                        float v = acc[mf][nf][r] + bias;
                        u16 hh = f2b(v);
                        Thi[(sq + r) * 264 + dcol] = hh;
                        Tlo[(sq + r) * 264 + dcol] = f2b(v - b2f(hh));
                    }
                }
            }
        }
        __syncthreads();
        #pragma unroll
        for (int rep = 0; rep < 4; rep++) {
            int g = tid + rep * 512;
            int s = g >> 5, d8 = (g & 31) * 8;
            size_t go = ((size_t)b * 512 + sbase + qt * 64 + s) * 1024 + n0 + d8;
            *(bf16x8*)(imgT_hi + go) = *(const bf16x8*)(&Thi[s * 264 + d8]);
            *(bf16x8*)(imgT_lo + go) = *(const bf16x8*)(&Tlo[s * 264 + d8]);
        }
    }
}

// ---------------------------------------------------------------------------
// k_logits: per b: C[iq][s] = wT . imgT^T (3-pass split), softmax over q,
// U -> global, Zp partials, diag u -> out.  BK=32, swizzled, dbuf prefetch,
// XCD-grouped (all 16 blocks of a b on one XCD).
// ---------------------------------------------------------------------------
__global__ __launch_bounds__(512) void k_logits(
    const u16* __restrict__ wTh, const u16* __restrict__ wTl,
    const u16* __restrict__ iTh, const u16* __restrict__ iTl,
    u16* __restrict__ U, float* __restrict__ Zp, float* __restrict__ out)
{
    const int bid0 = blockIdx.x;
    const int bid = (bid0 & 7) * 64 + (bid0 >> 3);   // XCD-grouped (512%8==0)
    const int b = bid >> 4, mt = (bid >> 1) & 7, nt = bid & 1;
    const int m0 = mt * 256, n0 = nt * 256;

    __shared__ char LDS[131072] __attribute__((aligned(16)));

    const int tid = threadIdx.x;
    const int wid = tid >> 6, lane = tid & 63;
    const int wr = wid >> 2, wc = wid & 3;
    const int l15 = lane & 15, l4 = lane >> 4;
    const int sw = (l15 >> 1) & 3;

    auto stage = [&](int buf, int k0) {
        char* base = LDS + buf * 65536;
        #pragma unroll
        for (int rep = 0; rep < 2; rep++) {
            int idx = tid + rep * 512;
            int row = idx >> 2, slot = idx & 3;
            int kb = (slot ^ ((row >> 1) & 3)) * 16;
            size_t ao = (size_t)(m0 + row) * 2048 + (size_t)k0 * 2 + kb;
            size_t bo = ((size_t)b * 512 + n0 + row) * 2048 + (size_t)k0 * 2 + kb;
            GLOAD(base + idx * 16, (const char*)wTh + ao);
            GLOAD(base + 16384 + idx * 16, (const char*)wTl + ao);
            GLOAD(base + 32768 + idx * 16, (const char*)iTh + bo);
            GLOAD(base + 49152 + idx * 16, (const char*)iTl + bo);
        }
    };

    f32x4 acc[8][4] = {};

    stage(0, 0);
    __syncthreads();
    int cur = 0;
    for (int k0 = 0; k0 < 1024; k0 += 32) {
        if (k0 + 32 < 1024) stage(cur ^ 1, k0 + 32);
        const char* Ah = LDS + cur * 65536;
        const char* Alo = Ah + 16384;
        const char* Bh = Ah + 32768;
        const char* Blo = Ah + 49152;
        bf16x8 ah[8], bh[4];
        #pragma unroll
        for (int mf = 0; mf < 8; mf++)
            ah[mf] = *(const bf16x8*)(Ah + (wr * 128 + mf * 16 + l15) * 64 + ((l4 ^ sw) * 16));
        #pragma unroll
        for (int nf = 0; nf < 4; nf++)
            bh[nf] = *(const bf16x8*)(Bh + (wc * 64 + nf * 16 + l15) * 64 + ((l4 ^ sw) * 16));
        #pragma unroll
        for (int mf = 0; mf < 8; mf++)
            #pragma unroll
            for (int nf = 0; nf < 4; nf++)
                acc[mf][nf] = __builtin_amdgcn_mfma_f32_16x16x32_bf16(ah[mf], bh[nf], acc[mf][nf], 0, 0, 0);
        #pragma unroll
        for (int mf = 0; mf < 8; mf++) {
            bf16x8 al = *(const bf16x8*)(Alo + (wr * 128 + mf * 16 + l15) * 64 + ((l4 ^ sw) * 16));
            #pragma unroll
            for (int nf = 0; nf < 4; nf++)
                acc[mf][nf] = __builtin_amdgcn_mfma_f32_16x16x32_bf16(al, bh[nf], acc[mf][nf], 0, 0, 0);
        }
        #pragma unroll
        for (int nf = 0; nf < 4; nf++) {
            bf16x8 bl = *(const bf16x8*)(Blo + (wc * 64 + nf * 16 + l15) * 64 + ((l4 ^ sw) * 16));
            #pragma unroll
            for (int mf = 0; mf < 8; mf++)
                acc[mf][nf] = __builtin_amdgcn_mfma_f32_16x16x32_bf16(ah[mf], bl, acc[mf][nf], 0, 0, 0);
        }
        __syncthreads();
        cur ^= 1;
    }

    float zacc[8][4] = {};
    #pragma unroll
    for (int il = 0; il < 2; il++) {
        int i_glob = mt * 4 + wr * 2 + il;
        bool diag = (i_glob == b);
        #pragma unroll
        for (int nf = 0; nf < 4; nf++) {
            int scol = n0 + wc * 64 + nf * 16 + l15;
            float m = -3.4e38f;
            #pragma unroll
            for (int mm = 0; mm < 4; mm++)
                #pragma unroll
                for (int r = 0; r < 4; r++)
                    m = fmaxf(m, acc[il * 4 + mm][nf][r]);
            m = fmaxf(m, __shfl_xor(m, 16));
            m = fmaxf(m, __shfl_xor(m, 32));
            float e[16], sum = 0.f;
            #pragma unroll
            for (int mm = 0; mm < 4; mm++)
                #pragma unroll
                for (int r = 0; r < 4; r++) {
                    float ev = __expf(acc[il * 4 + mm][nf][r] - m);
                    e[mm * 4 + r] = ev; sum += ev;
                }
            sum += __shfl_xor(sum, 16);
            sum += __shfl_xor(sum, 32);
            float inv = 1.f / sum;
            #pragma unroll
            for (int mm = 0; mm < 4; mm++)
                #pragma unroll
                for (int r = 0; r < 4; r++) {
                    float u = __expf(4.f * e[mm * 4 + r] * inv);   // in [1, e^4]
                    u16 ub = f2b(u);
                    zacc[il * 4 + mm][r] += b2f(ub);
                    int iqrow = m0 + wr * 128 + (il * 4 + mm) * 16 + l4 * 4 + r;
                    U[((size_t)b * 2048 + iqrow) * 512 + scol] = ub;
                    if (diag) {
                        int q = iqrow & 63;
                        out[1024 + ((size_t)i_glob * 64 + q) * 512 + scol] = u;
                    }
                }
        }
    }
    #pragma unroll
    for (int mf = 0; mf < 8; mf++)
        #pragma unroll
        for (int r = 0; r < 4; r++) {
            float z = zacc[mf][r];
            z += __shfl_xor(z, 1); z += __shfl_xor(z, 2);
            z += __shfl_xor(z, 4); z += __shfl_xor(z, 8);
            if (l15 == 0) {
                int iqrow = m0 + wr * 128 + mf * 16 + l4 * 4 + r;
                Zp[((size_t)b * 2048 + iqrow) * 8 + nt * 4 + wc] = z;
            }
        }
}

// ---------------------------------------------------------------------------
// k_zat: grid-fused zred (256 blocks) + attmap2 (32 blocks). grid 288.
// ---------------------------------------------------------------------------
__global__ __launch_bounds__(256) void k_zat(
    const float* __restrict__ Zp, float* __restrict__ invZf, float* __restrict__ out)
{
    const int bid = blockIdx.x;
    const int tid = threadIdx.x;
    if (bid < 256) {
        int gi = bid * 256 + tid;
        float4 z0 = *(const float4*)(Zp + (size_t)gi * 8);
        float4 z1 = *(const float4*)(Zp + (size_t)gi * 8 + 4);
        invZf[gi] = 1.f / (z0.x + z0.y + z0.z + z0.w + z1.x + z1.y + z1.z + z1.w);
    } else {
        const int i = bid - 256;
        float* am = out + 1024 + (size_t)i * Q_DIM * S_DIM;
        int q = tid >> 2, ch = tid & 3;
        float s = 0.f;
        for (int ss = ch * 128; ss < ch * 128 + 128; ss++) s += am[(size_t)q * S_DIM + ss];
        s += __shfl_xor(s, 1);
        s += __shfl_xor(s, 2);
        float iz = 1.f / s;
        for (int ss = ch * 128; ss < ch * 128 + 128; ss++) am[(size_t)q * S_DIM + ss] *= iz;
    }
}

// ---------------------------------------------------------------------------
// k_wctx: per b: C[d][iq] = img_hi . U^T, K=512, BK=32 (LDS 66KB -> 2
// blocks/CU), swizzled, dbuf prefetch, XCD-grouped.
// Epilogue: v = acc*invZ*(wThi+wTlo) -> vbuf; ssq partials.
// ---------------------------------------------------------------------------
__global__ __launch_bounds__(512) void k_wctx(
    const u16* __restrict__ img_hi, const u16* __restrict__ U,
    const float* __restrict__ invZf,
    const u16* __restrict__ wTh, const u16* __restrict__ wTl,
    u16* __restrict__ vbuf, float* __restrict__ ssqp)
{
    const int bid0 = blockIdx.x;
    const int bid = (bid0 & 7) * 128 + (bid0 >> 3);   // XCD-grouped (1024%8==0)
    const int b = bid >> 5, mt = (bid >> 3) & 3, nt = bid & 7;
    const int m0 = mt * 256, n0 = nt * 256;

    __shared__ char LDS[65536] __attribute__((aligned(16)));   // 2buf x {A 16K, B 16K}
    __shared__ float izS[256];

    const int tid = threadIdx.x;
    const int wid = tid >> 6, lane = tid & 63;
    const int wr = wid >> 2, wc = wid & 3;
    const int l15 = lane & 15, l4 = lane >> 4;
    const int sw = (l15 >> 1) & 3;

    if (tid < 256) izS[tid] = invZf[b * 2048 + n0 + tid];

    auto stage = [&](int buf, int k0) {
        char* base = LDS + buf * 32768;
        #pragma unroll
        for (int rep = 0; rep < 2; rep++) {
            int idx = tid + rep * 512;
            int row = idx >> 2, slot = idx & 3;
            int kb = (slot ^ ((row >> 1) & 3)) * 16;
            GLOAD(base + idx * 16, (const char*)img_hi + ((size_t)b * 1024 + m0 + row) * 1024 + (size_t)k0 * 2 + kb);
            GLOAD(base + 16384 + idx * 16, (const char*)U + ((size_t)b * 2048 + n0 + row) * 1024 + (size_t)k0 * 2 + kb);
        }
    };

    f32x4 acc[8][4] = {};

    stage(0, 0);
    __syncthreads();
    int cur = 0;
    for (int k0 = 0; k0 < 512; k0 += 32) {
        if (k0 + 32 < 512) stage(cur ^ 1, k0 + 32);
        const char* At = LDS + cur * 32768;
        const char* Bt = At + 16384;
        bf16x8 a[8], bb[4];
        #pragma unroll
        for (int mf = 0; mf < 8; mf++)
            a[mf] = *(const bf16x8*)(At + (wr * 128 + mf * 16 + l15) * 64 + ((l4 ^ sw) * 16));
        #pragma unroll
        for (int nf = 0; nf < 4; nf++)
            bb[nf] = *(const bf16x8*)(Bt + (wc * 64 + nf * 16 + l15) * 64 + ((l4 ^ sw) * 16));
        #pragma unroll
        for (int mf = 0; mf < 8; mf++)
            #pragma unroll
            for (int nf = 0; nf < 4; nf++)
                acc[mf][nf] = __builtin_amdgcn_mfma_f32_16x16x32_bf16(a[mf], bb[nf], acc[mf][nf], 0, 0, 0);
        __syncthreads();
        cur ^= 1;
    }

    #pragma unroll
    for (int nf = 0; nf < 4; nf++) {
        int col = wc * 64 + nf * 16 + l15;
        int iq = n0 + col;
        float iz = izS[col];
        size_t wtoff = (size_t)iq * 1024;
        float s_nf = 0.f;
        #pragma unroll
        for (int mf = 0; mf < 8; mf++) {
            int d0 = m0 + wr * 128 + mf * 16 + l4 * 4;
            ushort4 wh = *(const ushort4*)(wTh + wtoff + d0);
            ushort4 wl = *(const ushort4*)(wTl + wtoff + d0);
            const u16* pwh = (const u16*)&wh;
            const u16* pwl = (const u16*)&wl;
            ushort4 vo;
            u16* pv = (u16*)&vo;
            #pragma unroll
            for (int r = 0; r < 4; r++) {
                float wv = b2f(pwh[r]) + b2f(pwl[r]);
                float v = acc[mf][nf][r] * iz * wv;
                s_nf = fmaf(v, v, s_nf);
                pv[r] = f2b(v);
            }
            *(ushort4*)(vbuf + ((size_t)b * 2048 + iq) * 1024 + d0) = vo;
        }
        s_nf += __shfl_xor(s_nf, 16);
        s_nf += __shfl_xor(s_nf, 32);
        if (l4 == 0) ssqp[((size_t)b * 2048 + iq) * 4 + mt] = s_nf;
    }
}

// ---------------------------------------------------------------------------
// k_postwg: grid-fused post (1024 blocks) + prep(wg->wgT) (256 blocks).
// grid 1280.
// ---------------------------------------------------------------------------
__global__ __launch_bounds__(256) void k_postwg(
    const u16* __restrict__ vbuf, const float* __restrict__ ssqp,
    float* __restrict__ invn_ws, u16* __restrict__ simave_bf,
    const float* __restrict__ wg, u16* __restrict__ wgT)
{
    __shared__ char SH[16640] __attribute__((aligned(16)));
    const int bid = blockIdx.x;
    const int tid = threadIdx.x;

    if (bid < 1024) {
        // ---- post
        const int pair = bid;
        float* invnS = (float*)SH;   // 64 floats
        if (tid < 64) {
            size_t o = ((size_t)pair * 64 + tid) * 4;
            float s = ssqp[o] + ssqp[o + 1] + ssqp[o + 2] + ssqp[o + 3];
            float n = 1.f / (sqrtf(s) + 1e-8f);
            invnS[tid] = n;
            invn_ws[pair * 64 + tid] = n;
        }
        __syncthreads();
        int d0 = tid * 4;
        ushort4 o4 = make_ushort4(0, 0, 0, 0);
        if (d0 < D_DIM) {
            float a0 = 0.f, a1 = 0.f, a2 = 0.f, a3 = 0.f;
            const u16* vb = vbuf + (size_t)pair * 65536;
            for (int q = 0; q < 64; q++) {
                float n = invnS[q];
                ushort4 v = *(const ushort4*)(vb + q * 1024 + d0);
                a0 = fmaf(b2f(v.x), n, a0); a1 = fmaf(b2f(v.y), n, a1);
                a2 = fmaf(b2f(v.z), n, a2); a3 = fmaf(b2f(v.w), n, a3);
            }
            o4.x = f2b(a0 * (1.f / 64.f)); o4.y = f2b(a1 * (1.f / 64.f));
            o4.z = f2b(a2 * (1.f / 64.f)); o4.w = f2b(a3 * (1.f / 64.f));
        }
        *(ushort4*)(simave_bf + (size_t)pair * 1024 + d0) = o4;
    } else {
        // ---- prep (wg -> wgT)
        int lb = bid - 1024;
        float (*t)[65] = (float(*)[65])SH;   // 16640 B
        int bd = lb & 15, be = lb >> 4;
        int tx = tid & 15, ty = tid >> 4;
        #pragma unroll
        for (int rr = 0; rr < 4; rr++) {
            int r = ty * 4 + rr;
            int d = bd * 64 + r;
            int e4 = be * 64 + tx * 4;
            float v0 = 0.f, v1 = 0.f, v2 = 0.f, v3 = 0.f;
            if (d < D_DIM) {
                if (e4 + 3 < D_DIM) {
                    float4 v = *reinterpret_cast<const float4*>(wg + (size_t)d * D_DIM + e4);
                    v0 = v.x; v1 = v.y; v2 = v.z; v3 = v.w;
                } else {
                    if (e4 + 0 < D_DIM) v0 = wg[(size_t)d * D_DIM + e4 + 0];
                    if (e4 + 1 < D_DIM) v1 = wg[(size_t)d * D_DIM + e4 + 1];
                    if (e4 + 2 < D_DIM) v2 = wg[(size_t)d * D_DIM + e4 + 2];
                    if (e4 + 3 < D_DIM) v3 = wg[(size_t)d * D_DIM + e4 + 3];
                }
            }
            t[r][tx * 4 + 0] = v0; t[r][tx * 4 + 1] = v1;
            t[r][tx * 4 + 2] = v2; t[r][tx * 4 + 3] = v3;
        }
        __syncthreads();
        #pragma unroll
        for (int rr = 0; rr < 4; rr++) {
            int r2 = ty * 4 + rr;
            int e = be * 64 + r2;
            int d0 = bd * 64 + tx * 4;
            ushort4 h;
            h.x = f2b(t[tx * 4 + 0][r2]); h.y = f2b(t[tx * 4 + 1][r2]);
            h.z = f2b(t[tx * 4 + 2][r2]); h.w = f2b(t[tx * 4 + 3][r2]);
            *reinterpret_cast<ushort4*>(wgT + (size_t)e * 1024 + d0) = h;
        }
    }
}

// ---------------------------------------------------------------------------
// k_g2M: g2[p][e] = tanh(simave . wg + bg) * wc  via bf16 MFMA.
// 128x128 tiles, grid 64, 256 thr, dbuf.
// ---------------------------------------------------------------------------
__global__ __launch_bounds__(256) void k_g2M(
    const u16* __restrict__ simave_bf, const u16* __restrict__ wgT,
    const float* __restrict__ bg, const float* __restrict__ wc,
    float* __restrict__ g2)
{
    const int mt = blockIdx.x >> 3, nt = blockIdx.x & 7;
    const int m0 = mt * 128, n0 = nt * 128;

    __shared__ char LDS[65536] __attribute__((aligned(16)));  // 2 x {A 16K, B 16K}
    __shared__ float bgS[128], wcS[128];

    const int tid = threadIdx.x;
    const int wid = tid >> 6, lane = tid & 63;
    const int wr = wid >> 1, wc_ = wid & 1;
    const int l15 = lane & 15, l4 = lane >> 4;
    const int sw = l15 & 7;

    if (tid < 128) {
        int e = n0 + tid;
        bgS[tid] = (e < D_DIM) ? bg[e] : 0.f;
        wcS[tid] = (e < D_DIM) ? wc[e] : 0.f;
    }

    auto stage = [&](int buf, int k0) {
        char* base = LDS + buf * 32768;
        #pragma unroll
        for (int rep = 0; rep < 4; rep++) {
            int idx = tid + rep * 256;
            int row = idx >> 3, slot = idx & 7;
            int kb = (slot ^ (row & 7)) * 16;
            GLOAD(base + idx * 16, (const char*)simave_bf + (size_t)(m0 + row) * 2048 + (size_t)k0 * 2 + kb);
            GLOAD(base + 16384 + idx * 16, (const char*)wgT + (size_t)(n0 + row) * 2048 + (size_t)k0 * 2 + kb);
        }
    };

    f32x4 acc[4][4] = {};

    stage(0, 0);
    __syncthreads();
    int cur = 0;
    for (int k0 = 0; k0 < 1024; k0 += 64) {
        if (k0 + 64 < 1024) stage(cur ^ 1, k0 + 64);
        const char* Al = LDS + cur * 32768;
        const char* Bl = Al + 16384;
        #pragma unroll
        for (int kf = 0; kf < 2; kf++) {
            bf16x8 a[4], bb[4];
            #pragma unroll
            for (int mf = 0; mf < 4; mf++)
                a[mf] = *(const bf16x8*)(Al + (wr * 64 + mf * 16 + l15) * 128 + (((kf * 4 + l4) ^ sw) * 16));
            #pragma unroll
            for (int nf = 0; nf < 4; nf++)
                bb[nf] = *(const bf16x8*)(Bl + (wc_ * 64 + nf * 16 + l15) * 128 + (((kf * 4 + l4) ^ sw) * 16));
            #pragma unroll
            for (int mf = 0; mf < 4; mf++)
                #pragma unroll
                for (int nf = 0; nf < 4; nf++)
                    acc[mf][nf] = __builtin_amdgcn_mfma_f32_16x16x32_bf16(a[mf], bb[nf], acc[mf][nf], 0, 0, 0);
        }
        __syncthreads();
        cur ^= 1;
    }

    #pragma unroll
    for (int mf = 0; mf < 4; mf++) {
        int p = m0 + wr * 64 + mf * 16 + l4 * 4;
        #pragma unroll
        for (int nf = 0; nf < 4; nf++) {
            int cl = wc_ * 64 + nf * 16 + l15;
            float bgv = bgS[cl], wcv = wcS[cl];
            #pragma unroll
            for (int r = 0; r < 4; r++)
                g2[(size_t)(p + r) * 1024 + n0 + cl] = ftanh(acc[mf][nf][r] + bgv) * wcv;
        }
    }
}

// ---------------------------------------------------------------------------
// k_saG: flat GEMM M=65536, N=1024, K=1024.  BK=32 (LDS 70KB -> 2 blocks/CU),
// swizzled, dbuf prefetch, nt-fast + XCD block swizzle.
// ---------------------------------------------------------------------------
__global__ __launch_bounds__(512) void k_saG(
    const u16* __restrict__ vbuf, const u16* __restrict__ wlT,
    const float* __restrict__ invn_ws, const float* __restrict__ g2_ws,
    const float* __restrict__ bl, float* __restrict__ wspart)
{
    const int bid = blockIdx.x;
    const int wg = (bid & 7) * 128 + (bid >> 3);
    const int mt = wg >> 2, nt = wg & 3;
    const int m0 = mt * 256, n0 = nt * 256;

    __shared__ char LDS[65536] __attribute__((aligned(16)));   // 2buf x {A 16K, B 16K}
    __shared__ float invnS[256];
    __shared__ float blS[256];
    __shared__ float g2S[4 * 256];

    const int tid = threadIdx.x;
    const int wid = tid >> 6, lane = tid & 63;
    const int wr = wid >> 2, wc = wid & 3;
    const int l15 = lane & 15, l4 = lane >> 4;
    const int sw = (l15 >> 1) & 3;

    if (tid < 256) {
        invnS[tid] = invn_ws[m0 + tid];
        int e = n0 + tid;
        blS[tid] = (e < D_DIM) ? bl[e] : 0.f;
    }
    #pragma unroll
    for (int rep = 0; rep < 2; rep++) {
        int idx = tid + rep * 512;
        int p = idx >> 8, el = idx & 255;
        g2S[idx] = g2_ws[(size_t)((m0 >> 6) + p) * 1024 + n0 + el];
    }

    auto stage = [&](int buf, int k0) {
        char* base = LDS + buf * 32768;
        #pragma unroll
        for (int rep = 0; rep < 2; rep++) {
            int idx = tid + rep * 512;
            int row = idx >> 2, slot = idx & 3;
            int kb = (slot ^ ((row >> 1) & 3)) * 16;
            GLOAD(base + idx * 16, (const char*)vbuf + (size_t)(m0 + row) * 2048 + (size_t)k0 * 2 + kb);
            GLOAD(base + 16384 + idx * 16, (const char*)wlT + (size_t)(n0 + row) * 2048 + (size_t)k0 * 2 + kb);
        }
    };

    f32x4 acc[8][4] = {};

    stage(0, 0);
    __syncthreads();
    int cur = 0;
    for (int k0 = 0; k0 < 1024; k0 += 32) {
        if (k0 + 32 < 1024) stage(cur ^ 1, k0 + 32);
        const char* Al = LDS + cur * 32768;
        const char* Bl = Al + 16384;
        bf16x8 a[8], bb[4];
        #pragma unroll
        for (int mf = 0; mf < 8; mf++)
            a[mf] = *(const bf16x8*)(Al + (wr * 128 + mf * 16 + l15) * 64 + ((l4 ^ sw) * 16));
        #pragma unroll
        for (int nf = 0; nf < 4; nf++)
            bb[nf] = *(const bf16x8*)(Bl + (wc * 64 + nf * 16 + l15) * 64 + ((l4 ^ sw) * 16));
        #pragma unroll
        for (int mf = 0; mf < 8; mf++)
            #pragma unroll
            for (int nf = 0; nf < 4; nf++)
                acc[mf][nf] = __builtin_amdgcn_mfma_f32_16x16x32_bf16(a[mf], bb[nf], acc[mf][nf], 0, 0, 0);
        __syncthreads();
        cur ^= 1;
    }

    #pragma unroll
    for (int mf = 0; mf < 8; mf++) {
        int mrow = wr * 128 + mf * 16 + l4 * 4;
        #pragma unroll
        for (int r = 0; r < 4; r++) {
            float inv = invnS[mrow + r];
            int p = (mrow + r) >> 6;
            float s = 0.f;
            #pragma unroll
            for (int nf = 0; nf < 4; nf++) {
                int el = wc * 64 + nf * 16 + l15;
                float x = acc[mf][nf][r] * inv + blS[el];
                s += ftanh(x) * g2S[p * 256 + el];
            }
            s += __shfl_xor(s, 1);
            s += __shfl_xor(s, 2);
            s += __shfl_xor(s, 4);
            s += __shfl_xor(s, 8);
            if (l15 == 0)
                wspart[(size_t)(nt * 4 + wc) * 65536 + m0 + mrow + r] = s;
        }
    }
}

// ---------------------------------------------------------------------------
// k_sa2: per pair: w[q] -> softmax -> new_global -> l2norm -> sigmoid -> out
// ---------------------------------------------------------------------------
__global__ __launch_bounds__(256) void k_sa2(
    const float* __restrict__ wspart, const float* __restrict__ invn_ws,
    const u16* __restrict__ vbuf, const float* __restrict__ capw,
    const float* __restrict__ capb, float* __restrict__ out)
{
    const int pair = blockIdx.x;
    const u16* vb = vbuf + (size_t)pair * 65536;

    __shared__ float wiS[64];
    __shared__ float red[8];

    const int tid = threadIdx.x;

    if (tid < 64) {
        float x = 0.f;
        #pragma unroll
        for (int c = 0; c < 16; c++) x += wspart[(size_t)c * 65536 + pair * 64 + tid];
        float m = x;
        #pragma unroll
        for (int mk = 1; mk < 64; mk <<= 1) m = fmaxf(m, __shfl_xor(m, mk));
        float e = __expf(x - m);
        float Z = e;
        #pragma unroll
        for (int mk = 1; mk < 64; mk <<= 1) Z += __shfl_xor(Z, mk);
        wiS[tid] = (e / Z) * invn_ws[pair * 64 + tid];
    }
    __syncthreads();

    float s1 = 0.f, s2 = 0.f;
    int d0 = tid * 4;
    if (d0 < D_DIM) {
        float a0 = 0.f, a1 = 0.f, a2 = 0.f, a3 = 0.f;
        for (int q = 0; q < 64; q++) {
            float wq = wiS[q];
            ushort4 v = *(const ushort4*)(vb + q * 1024 + d0);
            a0 = fmaf(wq, b2f(v.x), a0); a1 = fmaf(wq, b2f(v.y), a1);
            a2 = fmaf(wq, b2f(v.z), a2); a3 = fmaf(wq, b2f(v.w), a3);
        }
        float4 cw4 = *(const float4*)(capw + d0);
        s1 = a0 * cw4.x + a1 * cw4.y + a2 * cw4.z + a3 * cw4.w;
        s2 = a0 * a0 + a1 * a1 + a2 * a2 + a3 * a3;
    }
    #pragma unroll
    for (int mk = 1; mk < 64; mk <<= 1) { s1 += __shfl_xor(s1, mk); s2 += __shfl_xor(s2, mk); }
    if ((tid & 63) == 0) { red[tid >> 6] = s1; red[4 + (tid >> 6)] = s2; }
    __syncthreads();
    if (tid == 0) {
        float S1 = red[0] + red[1] + red[2] + red[3];
        float S2 = red[4] + red[5] + red[6] + red[7];
        float val = S1 / (sqrtf(S2) + 1e-8f) + capb[0];
        out[pair] = 1.f / (1.f + __expf(-val));
    }
}

// ---------------------------------------------------------------------------
extern "C" void kernel_launch(void* const* d_in, const int* in_sizes, int n_in,
                              void* d_out, int out_size, void* d_ws, size_t ws_size,
                              hipStream_t stream)
{
    const float* feat_l = (const float*)d_in[0];
    const float* feat_f = (const float*)d_in[1];
    const float* words  = (const float*)d_in[2];
    const float* conv_w = (const float*)d_in[3];
    const float* conv_b = (const float*)d_in[4];
    const float* sa_wl  = (const float*)d_in[5];
    const float* sa_bl  = (const float*)d_in[6];
    const float* sa_wg  = (const float*)d_in[7];
    const float* sa_bg  = (const float*)d_in[8];
    const float* sa_wc  = (const float*)d_in[9];
    // d_in[10] = sa_bc: constant pre-softmax shift -> result-invariant
    const float* cap_w  = (const float*)d_in[11];
    const float* cap_b  = (const float*)d_in[12];
    float* out = (float*)d_out;

    char* ws = (char*)d_ws;
    // Overlay layout (bytes), peak 253,755,392:
    //   [0,134.2M): featT_hi@0, featT_lo@33.5M (prepAll->convG);
    //               imgT_hi@67.1M, imgT_lo@100.7M (convG->logits); vbuf@0 (wctx->sa2)
    //   [134.2M,167.8M): img_hi (convG->wctx); wgT@134.2M (postwg->g2M)
    //   [167.8M,234.9M): U@167.8M (logits->wctx); wspart@167.8M (saG->sa2)
    //   [234.9M,243.3M): wT_hi,wT_lo (prepAll->wctx); simave_bf@234.9M (postwg->g2M)
    //   [243.3M,247.5M): cw_hi,cw_lo (prepAll->convG); then Zp, invZf, ssqp, invn
    //   [247.5M,249.6M): wlT ; [249.6M,253.76M): g2 fp32 [1024][1024]
    u16*   featT_hi  = (u16*)(ws);
    u16*   featT_lo  = (u16*)(ws + 33554432);
    u16*   imgT_hi   = (u16*)(ws + 67108864);
    u16*   imgT_lo   = (u16*)(ws + 100663296);
    u16*   vbuf      = (u16*)(ws);
    u16*   img_hi    = (u16*)(ws + 134217728);
    u16*   wgT       = (u16*)(ws + 134217728);
    u16*   U         = (u16*)(ws + 167772160);
    float* wspart    = (float*)(ws + 167772160);
    u16*   wT_hi     = (u16*)(ws + 234881024);
    u16*   simave_bf = (u16*)(ws + 234881024);
    u16*   wT_lo     = (u16*)(ws + 239075328);
    u16*   cw_hi     = (u16*)(ws + 243269632);
    float* Zp        = (float*)(ws + 243269632);
    u16*   cw_lo     = (u16*)(ws + 245366784);
    float* invZf     = (float*)(ws + 245366784);
    float* ssqp      = (float*)(ws + 245628928);
    float* invn      = (float*)(ws + 246677504);
    u16*   wlT       = (u16*)(ws + 247463936);
    float* g2        = (float*)(ws + 249561088);

    hipLaunchKernelGGL(k_prepAll, dim3(5888), dim3(256), 0, stream,
                       feat_l, feat_f, conv_w, words, sa_wl,
                       featT_hi, featT_lo, cw_hi, cw_lo, wT_hi, wT_lo, wlT);
    hipLaunchKernelGGL(k_convG, dim3(256), dim3(512), 0, stream,
                       featT_hi, featT_lo, cw_hi, cw_lo, conv_b,
                       img_hi, imgT_hi, imgT_lo);
    hipLaunchKernelGGL(k_logits, dim3(512), dim3(512), 0, stream,
                       wT_hi, wT_lo, imgT_hi, imgT_lo, U, Zp, out);
    hipLaunchKernelGGL(k_zat, dim3(288), dim3(256), 0, stream, Zp, invZf, out);
    hipLaunchKernelGGL(k_wctx, dim3(1024), dim3(512), 0, stream,
                       img_hi, U, invZf, wT_hi, wT_lo, vbuf, ssqp);
    hipLaunchKernelGGL(k_postwg, dim3(1280), dim3(256), 0, stream,
                       vbuf, ssqp, invn, simave_bf, sa_wg, wgT);
    hipLaunchKernelGGL(k_g2M, dim3(64), dim3(256), 0, stream,
                       simave_bf, wgT, sa_bg, sa_wc, g2);
    hipLaunchKernelGGL(k_saG, dim3(1024), dim3(512), 0, stream,
                       vbuf, wlT, invn, g2, sa_bl, wspart);
    hipLaunchKernelGGL(k_sa2, dim3(1024), dim3(256), 0, stream,
                       wspart, invn, vbuf, cap_w, cap_b, out);
}